// Round 1
// baseline (511.570 us; speedup 1.0000x reference)
//
#include <hip/hip_runtime.h>

#define B_GRAPHS 1024
#define NN 360
#define HH 8
#define DD 256
#define D4 64   // DD / 4 float4 lanes

// ---------------------------------------------------------------------------
// Kernel 1: column softmax of w[360][8] over axis 0 (nodes), one head per wave.
// ---------------------------------------------------------------------------
__global__ __launch_bounds__(512) void softmax_kernel(const float* __restrict__ w,
                                                      float* __restrict__ attn) {
    const int h    = threadIdx.x >> 6;   // 8 waves, one head each
    const int lane = threadIdx.x & 63;

    float m = -1e30f;
    for (int n = lane; n < NN; n += 64) m = fmaxf(m, w[n * HH + h]);
    #pragma unroll
    for (int off = 32; off > 0; off >>= 1) m = fmaxf(m, __shfl_xor(m, off));

    float s = 0.f;
    for (int n = lane; n < NN; n += 64) s += __expf(w[n * HH + h] - m);
    #pragma unroll
    for (int off = 32; off > 0; off >>= 1) s += __shfl_xor(s, off);

    const float inv = 1.f / s;
    for (int n = lane; n < NN; n += 64)
        attn[n * HH + h] = __expf(w[n * HH + h] - m) * inv;
}

// ---------------------------------------------------------------------------
// Kernel 2: out[b][h][d] = sum_n x[b][n][d] * attn[n][h]
// One block per graph. Lane = float4 column slice, waves split n.
// ---------------------------------------------------------------------------
__global__ __launch_bounds__(256) void pool_kernel(const float4* __restrict__ x,
                                                   const float* __restrict__ attn,
                                                   float4* __restrict__ out) {
    __shared__ float4 s_attn[NN][2];        // attn row = 8 floats = 2 float4 (11.5 KB)
    __shared__ float4 s_red[4][HH][D4];     // cross-wave reduction buffer (32 KB)

    const int b    = blockIdx.x;
    const int lane = threadIdx.x & 63;
    const int wave = threadIdx.x >> 6;

    // stage attn into LDS (broadcast source for all lanes)
    {
        float* s_attn_f = (float*)s_attn;
        for (int i = threadIdx.x; i < NN * HH; i += 256) s_attn_f[i] = attn[i];
    }
    __syncthreads();

    const float4* xb = x + (size_t)b * NN * D4 + lane;

    float4 acc[HH];
    #pragma unroll
    for (int h = 0; h < HH; ++h) acc[h] = make_float4(0.f, 0.f, 0.f, 0.f);

    #pragma unroll 5
    for (int n = wave; n < NN; n += 4) {
        const float4 xv = xb[(size_t)n * D4];          // coalesced 1 KB/wave row read
        const float4 a0 = s_attn[n][0];                // same-address LDS broadcast
        const float4 a1 = s_attn[n][1];
        const float av[8] = {a0.x, a0.y, a0.z, a0.w, a1.x, a1.y, a1.z, a1.w};
        #pragma unroll
        for (int h = 0; h < HH; ++h) {
            acc[h].x = fmaf(xv.x, av[h], acc[h].x);
            acc[h].y = fmaf(xv.y, av[h], acc[h].y);
            acc[h].z = fmaf(xv.z, av[h], acc[h].z);
            acc[h].w = fmaf(xv.w, av[h], acc[h].w);
        }
    }

    #pragma unroll
    for (int h = 0; h < HH; ++h) s_red[wave][h][lane] = acc[h];
    __syncthreads();

    // 8 heads x 64 float4 = 512 output slots; 256 threads -> 2 each
    for (int s = threadIdx.x; s < HH * D4; s += 256) {
        const int h = s >> 6, l = s & 63;
        const float4 r0 = s_red[0][h][l];
        const float4 r1 = s_red[1][h][l];
        const float4 r2 = s_red[2][h][l];
        const float4 r3 = s_red[3][h][l];
        float4 o;
        o.x = r0.x + r1.x + r2.x + r3.x;
        o.y = r0.y + r1.y + r2.y + r3.y;
        o.z = r0.z + r1.z + r2.z + r3.z;
        o.w = r0.w + r1.w + r2.w + r3.w;
        out[(size_t)b * (HH * D4) + s] = o;
    }
}

extern "C" void kernel_launch(void* const* d_in, const int* in_sizes, int n_in,
                              void* d_out, int out_size, void* d_ws, size_t ws_size,
                              hipStream_t stream) {
    const float* x = (const float*)d_in[0];   // [B*360, 256] fp32
    // d_in[1] = batch (int64) — layout is dense/sorted by construction; unused.
    const float* w = (const float*)d_in[2];   // [360, 8] fp32
    float* attn = (float*)d_ws;               // 360*8 floats scratch

    softmax_kernel<<<1, 512, 0, stream>>>(w, attn);
    pool_kernel<<<B_GRAPHS, 256, 0, stream>>>((const float4*)x, attn, (float4*)d_out);
}

// Round 2
// 509.914 us; speedup vs baseline: 1.0032x; 1.0032x over previous
//
#include <hip/hip_runtime.h>

#define B_GRAPHS 1024
#define NN 360
#define HH 8
#define DD 256
#define D4 64   // DD / 4 float4 lanes

// ---------------------------------------------------------------------------
// Fused kernel: per-block softmax(w) -> LDS, then
// out[b][h][d] = sum_n x[b][n][d] * attn[n][h]
// One block per graph, 256 threads (4 waves). Lane = float4 column slice,
// waves split n (mod 4). LDS: attn buffer overlaid by reduction buffer.
// ---------------------------------------------------------------------------
__global__ __launch_bounds__(256, 4) void roigp_fused_kernel(
        const float4* __restrict__ x,
        const float*  __restrict__ w,
        float4* __restrict__ out) {
    // 32 KB shared: attn[360*8] floats (11.52 KB) overlaid by red[4][8][64] float4
    __shared__ __align__(16) char smem[4 * HH * D4 * 16];
    float* s_attn = (float*)smem;
    float4 (*s_red)[HH][D4] = (float4 (*)[HH][D4])smem;

    const int b    = blockIdx.x;
    const int lane = threadIdx.x & 63;
    const int wave = threadIdx.x >> 6;

    // ---- Phase 0: softmax over nodes, per head. Wave w handles heads w, w+4.
    #pragma unroll
    for (int h = wave; h < HH; h += 4) {
        float m = -1e30f;
        for (int n = lane; n < NN; n += 64) m = fmaxf(m, w[n * HH + h]);
        #pragma unroll
        for (int off = 32; off > 0; off >>= 1) m = fmaxf(m, __shfl_xor(m, off));

        float s = 0.f;
        for (int n = lane; n < NN; n += 64) s += __expf(w[n * HH + h] - m);
        #pragma unroll
        for (int off = 32; off > 0; off >>= 1) s += __shfl_xor(s, off);

        const float inv = 1.f / s;
        for (int n = lane; n < NN; n += 64)
            s_attn[n * HH + h] = __expf(w[n * HH + h] - m) * inv;
    }
    __syncthreads();

    // ---- Phase 1: main streaming loop. Wave reads 1 KB/iter, coalesced.
    const float4* xb = x + (size_t)b * NN * D4 + lane;

    float4 acc[HH];
    #pragma unroll
    for (int h = 0; h < HH; ++h) acc[h] = make_float4(0.f, 0.f, 0.f, 0.f);

    #pragma unroll 5
    for (int n = wave; n < NN; n += 4) {
        const float4 xv = xb[(size_t)n * D4];
        const float4 a0 = ((const float4*)(s_attn + n * HH))[0];  // broadcast
        const float4 a1 = ((const float4*)(s_attn + n * HH))[1];
        const float av[8] = {a0.x, a0.y, a0.z, a0.w, a1.x, a1.y, a1.z, a1.w};
        #pragma unroll
        for (int h = 0; h < HH; ++h) {
            acc[h].x = fmaf(xv.x, av[h], acc[h].x);
            acc[h].y = fmaf(xv.y, av[h], acc[h].y);
            acc[h].z = fmaf(xv.z, av[h], acc[h].z);
            acc[h].w = fmaf(xv.w, av[h], acc[h].w);
        }
    }

    // ---- Phase 2: cross-wave reduction. attn is dead; reuse the LDS.
    __syncthreads();   // all waves done READING s_attn before overwrite
    #pragma unroll
    for (int h = 0; h < HH; ++h) s_red[wave][h][lane] = acc[h];
    __syncthreads();

    // 8 heads x 64 float4 = 512 output slots; 256 threads -> 2 each
    #pragma unroll
    for (int s = threadIdx.x; s < HH * D4; s += 256) {
        const int h = s >> 6, l = s & 63;
        const float4 r0 = s_red[0][h][l];
        const float4 r1 = s_red[1][h][l];
        const float4 r2 = s_red[2][h][l];
        const float4 r3 = s_red[3][h][l];
        float4 o;
        o.x = r0.x + r1.x + r2.x + r3.x;
        o.y = r0.y + r1.y + r2.y + r3.y;
        o.z = r0.z + r1.z + r2.z + r3.z;
        o.w = r0.w + r1.w + r2.w + r3.w;
        out[(size_t)b * (HH * D4) + s] = o;
    }
}

extern "C" void kernel_launch(void* const* d_in, const int* in_sizes, int n_in,
                              void* d_out, int out_size, void* d_ws, size_t ws_size,
                              hipStream_t stream) {
    const float* x = (const float*)d_in[0];   // [B*360, 256] fp32
    // d_in[1] = batch (int64) — dense/sorted by construction; unused.
    const float* w = (const float*)d_in[2];   // [360, 8] fp32

    roigp_fused_kernel<<<B_GRAPHS, 256, 0, stream>>>(
        (const float4*)x, w, (float4*)d_out);
}